// Round 1
// baseline (3034.280 us; speedup 1.0000x reference)
//
#include <hip/hip_runtime.h>

// ---------------------------------------------------------------------------
// MultiHeadAttention_60000693125780  (fp32 correctness-first baseline)
//
// Shapes: B=4,S=8,D=512,R=32,C=8,H=8,dep=1, f=3
// conv1: N=32 images (B*S), C=512ch, 32x8 spatial
// conv2: N=4  images (B),   C=512ch, 8x256 spatial
//
// Index algebra (from the reshape/transpose chain):
//   q6[nn,dd,rr,h] = Yq[n=4h+(nn>>3)][d=64(nn&7)+(dd>>3)][r=4(dd&7)+(rr>>3)][c=rr&7]
//   Qm[nn][dd][t], t = h*32 + rr  (so scores = Qm . Km^T per nn, K=256)
//   conv epilogue scatter:  nn=(n&3)*8+(d>>6), dd=(d&63)*8+(y>>2),
//                           t=(n>>2)*32+(y&3)*8+x         (contiguous over x!)
//   sa[b2][d2][s2][w]: b2=nn>>3, s2=nn&7, q'=(w>>3)*16+(w&7)*2+(d2>>8),
//                      rr=(d2>>3)&31, h=d2&7  -> src t = h*32+rr
//   y out flat = b2*2^20 + co*2048 + (s2*256+w)          (contiguous over w)
// ---------------------------------------------------------------------------

#define F4(p) (*(const float4*)(p))

// ---- weight transpose: W[co][ci][ky][kx] -> Wt[tap][ci][co], tap=ky*3+kx ----
__global__ __launch_bounds__(256) void k_transpose_w(const float* __restrict__ W,
                                                     float* __restrict__ Wt) {
    int tid = blockIdx.x * 256 + threadIdx.x;   // 512*512*9 = 2359296 exact
    int co  = tid & 511;
    int ci  = (tid >> 9) & 511;
    int tap = tid >> 18;
    Wt[tid] = W[(co * 512 + ci) * 9 + tap];
}

// ---- conv 3x3 SAME over (32,512,32,8), epilogue scatters into Qm layout ----
__global__ __launch_bounds__(256) void k_conv_qkv(const float* __restrict__ X,
                                                  const float* __restrict__ Wt,
                                                  const float* __restrict__ bias,
                                                  float* __restrict__ Qm) {
    __shared__ float As[16 * 128];
    __shared__ float Bs[16 * 64];
    const int tid = threadIdx.x;
    const int n   = blockIdx.x >> 1;            // image 0..31
    const int p0  = (blockIdx.x & 1) * 128;     // pixel tile (image has 256 px)
    const int co0 = blockIdx.y * 64;
    const int tx = tid & 15, ty = tid >> 4;     // 16 co-groups x 16 pix-groups

    float acc[8][4];
#pragma unroll
    for (int j = 0; j < 4; ++j) {
        float bb = bias[co0 + tx * 4 + j];
#pragma unroll
        for (int i = 0; i < 8; ++i) acc[i][j] = bb;
    }

    const float* Xn = X + n * (512 * 256);

    for (int tap = 0; tap < 9; ++tap) {
        const int dy = tap / 3 - 1, dx = tap % 3 - 1;
        const int shift = dy * 8 + dx;
        for (int c0 = 0; c0 < 512; c0 += 16) {
#pragma unroll
            for (int l = 0; l < 8; ++l) {       // stage A: 128 px x 16 ci
                int e = tid + l * 256;
                int kk = e >> 7, pp = e & 127;
                int p = p0 + pp;
                int y = (p >> 3) + dy, x = (p & 7) + dx;
                float v = 0.f;
                if ((unsigned)y < 32u && (unsigned)x < 8u)
                    v = Xn[(c0 + kk) * 256 + p + shift];
                As[kk * 128 + pp] = v;
            }
#pragma unroll
            for (int l = 0; l < 4; ++l) {       // stage B: 16 ci x 64 co
                int e = tid + l * 256;
                int kk = e >> 6, cc = e & 63;
                Bs[kk * 64 + cc] = Wt[(tap * 512 + c0 + kk) * 512 + co0 + cc];
            }
            __syncthreads();
#pragma unroll
            for (int kk = 0; kk < 16; ++kk) {
                float4 a0 = F4(&As[kk * 128 + ty * 8]);
                float4 a1 = F4(&As[kk * 128 + ty * 8 + 4]);
                float4 b  = F4(&Bs[kk * 64 + tx * 4]);
                float av[8] = {a0.x, a0.y, a0.z, a0.w, a1.x, a1.y, a1.z, a1.w};
                float bv[4] = {b.x, b.y, b.z, b.w};
#pragma unroll
                for (int i = 0; i < 8; ++i)
#pragma unroll
                    for (int j = 0; j < 4; ++j) acc[i][j] += av[i] * bv[j];
            }
            __syncthreads();
        }
    }

    // epilogue: scatter into Qm[nn][dd][t]; 8 pixels = one full x-row (contig t)
    const int h = n >> 2, nl = n & 3;
    const int pb = p0 + ty * 8;                 // 8-aligned => y const, x=0..7
    const int y = pb >> 3;
#pragma unroll
    for (int j = 0; j < 4; ++j) {
        int d  = co0 + tx * 4 + j;
        int nn = nl * 8 + (d >> 6);
        int dd = (d & 63) * 8 + (y >> 2);
        int t0 = h * 32 + (y & 3) * 8;
        float* dst = &Qm[(nn * 512 + dd) * 256 + t0];
        *(float4*)dst       = make_float4(acc[0][j], acc[1][j], acc[2][j], acc[3][j]);
        *(float4*)(dst + 4) = make_float4(acc[4][j], acc[5][j], acc[6][j], acc[7][j]);
    }
}

// ---- output conv 3x3 SAME over (4,512,8,256), writes y to d_out region 0 ----
__global__ __launch_bounds__(256) void k_conv_o(const float* __restrict__ X,
                                                const float* __restrict__ Wt,
                                                const float* __restrict__ bias,
                                                float* __restrict__ Y) {
    __shared__ float As[16 * 128];
    __shared__ float Bs[16 * 64];
    const int tid = threadIdx.x;
    const int n   = blockIdx.x >> 4;            // image 0..3 (2048 px each)
    const int p0  = (blockIdx.x & 15) * 128;
    const int co0 = blockIdx.y * 64;
    const int tx = tid & 15, ty = tid >> 4;

    float acc[8][4];
#pragma unroll
    for (int j = 0; j < 4; ++j) {
        float bb = bias[co0 + tx * 4 + j];
#pragma unroll
        for (int i = 0; i < 8; ++i) acc[i][j] = bb;
    }

    const float* Xn = X + n * (512 * 2048);

    for (int tap = 0; tap < 9; ++tap) {
        const int dy = tap / 3 - 1, dx = tap % 3 - 1;
        const int shift = dy * 256 + dx;
        for (int c0 = 0; c0 < 512; c0 += 16) {
#pragma unroll
            for (int l = 0; l < 8; ++l) {
                int e = tid + l * 256;
                int kk = e >> 7, pp = e & 127;
                int p = p0 + pp;
                int y = (p >> 8) + dy, x = (p & 255) + dx;
                float v = 0.f;
                if ((unsigned)y < 8u && (unsigned)x < 256u)
                    v = Xn[(c0 + kk) * 2048 + p + shift];
                As[kk * 128 + pp] = v;
            }
#pragma unroll
            for (int l = 0; l < 4; ++l) {
                int e = tid + l * 256;
                int kk = e >> 6, cc = e & 63;
                Bs[kk * 64 + cc] = Wt[(tap * 512 + c0 + kk) * 512 + co0 + cc];
            }
            __syncthreads();
#pragma unroll
            for (int kk = 0; kk < 16; ++kk) {
                float4 a0 = F4(&As[kk * 128 + ty * 8]);
                float4 a1 = F4(&As[kk * 128 + ty * 8 + 4]);
                float4 b  = F4(&Bs[kk * 64 + tx * 4]);
                float av[8] = {a0.x, a0.y, a0.z, a0.w, a1.x, a1.y, a1.z, a1.w};
                float bv[4] = {b.x, b.y, b.z, b.w};
#pragma unroll
                for (int i = 0; i < 8; ++i)
#pragma unroll
                    for (int j = 0; j < 4; ++j) acc[i][j] += av[i] * bv[j];
            }
            __syncthreads();
        }
    }

    const int pb = p0 + ty * 8;
#pragma unroll
    for (int j = 0; j < 4; ++j) {
        int co = co0 + tx * 4 + j;
        float* dst = &Y[n * 1048576 + co * 2048 + pb];
        *(float4*)dst       = make_float4(acc[0][j], acc[1][j], acc[2][j], acc[3][j]);
        *(float4*)(dst + 4) = make_float4(acc[4][j], acc[5][j], acc[6][j], acc[7][j]);
    }
}

// ---- scores: Sc[nn][q'][k'] = sum_t Qm[nn][q'][t]*Km[nn][k'][t] (K=256) ----
__global__ __launch_bounds__(256) void k_scores(const float* __restrict__ Qm,
                                                const float* __restrict__ Km,
                                                float* __restrict__ Sc) {
    __shared__ float As[16 * 132];   // [kk][qq], stride 132 kills store conflicts
    __shared__ float Bs[16 * 68];    // [kk][cc]
    const int tid = threadIdx.x;
    const int q0 = blockIdx.x * 128, k0 = blockIdx.y * 64, nn = blockIdx.z;
    const float* A = Qm + nn * 131072;
    const float* B = Km + nn * 131072;
    const int tx = tid & 15, ty = tid >> 4;
    float acc[8][4];
#pragma unroll
    for (int i = 0; i < 8; ++i)
#pragma unroll
        for (int j = 0; j < 4; ++j) acc[i][j] = 0.f;

    for (int t0 = 0; t0 < 256; t0 += 16) {
#pragma unroll
        for (int l = 0; l < 2; ++l) {
            int s = tid + l * 256;
            int qq = s >> 2, tq = (s & 3) * 4;
            float4 v = F4(&A[(q0 + qq) * 256 + t0 + tq]);
            As[(tq + 0) * 132 + qq] = v.x;
            As[(tq + 1) * 132 + qq] = v.y;
            As[(tq + 2) * 132 + qq] = v.z;
            As[(tq + 3) * 132 + qq] = v.w;
        }
        {
            int cc = tid >> 2, tq = (tid & 3) * 4;
            float4 v = F4(&B[(k0 + cc) * 256 + t0 + tq]);
            Bs[(tq + 0) * 68 + cc] = v.x;
            Bs[(tq + 1) * 68 + cc] = v.y;
            Bs[(tq + 2) * 68 + cc] = v.z;
            Bs[(tq + 3) * 68 + cc] = v.w;
        }
        __syncthreads();
#pragma unroll
        for (int kk = 0; kk < 16; ++kk) {
            float4 a0 = F4(&As[kk * 132 + ty * 8]);
            float4 a1 = F4(&As[kk * 132 + ty * 8 + 4]);
            float4 b  = F4(&Bs[kk * 68 + tx * 4]);
            float av[8] = {a0.x, a0.y, a0.z, a0.w, a1.x, a1.y, a1.z, a1.w};
            float bv[4] = {b.x, b.y, b.z, b.w};
#pragma unroll
            for (int i = 0; i < 8; ++i)
#pragma unroll
                for (int j = 0; j < 4; ++j) acc[i][j] += av[i] * bv[j];
        }
        __syncthreads();
    }
    float* C = Sc + nn * 262144;
#pragma unroll
    for (int i = 0; i < 8; ++i)
        *(float4*)&C[(q0 + ty * 8 + i) * 512 + k0 + tx * 4] =
            make_float4(acc[i][0], acc[i][1], acc[i][2], acc[i][3]);
}

// ---- softmax in-place over rows of 512 (16384 rows) ----
__global__ __launch_bounds__(256) void k_softmax(float* __restrict__ Sc) {
    __shared__ float red[8];
    float* p = Sc + (size_t)blockIdx.x * 512;
    const int tid = threadIdx.x;
    float x0 = p[tid], x1 = p[tid + 256];
    float m = fmaxf(x0, x1);
#pragma unroll
    for (int off = 32; off; off >>= 1) m = fmaxf(m, __shfl_xor(m, off));
    if ((tid & 63) == 0) red[tid >> 6] = m;
    __syncthreads();
    m = fmaxf(fmaxf(red[0], red[1]), fmaxf(red[2], red[3]));
    float e0 = __expf(x0 - m), e1 = __expf(x1 - m);
    float s = e0 + e1;
#pragma unroll
    for (int off = 32; off; off >>= 1) s += __shfl_xor(s, off);
    if ((tid & 63) == 0) red[4 + (tid >> 6)] = s;
    __syncthreads();
    s = red[4] + red[5] + red[6] + red[7];
    float inv = 1.0f / s;
    p[tid] = e0 * inv;
    p[tid + 256] = e1 * inv;
}

// ---- PV: Oa[nn][q'][t] = sum_k attn[nn][q'][k] * Vm[nn][k][t] (K=512) ----
__global__ __launch_bounds__(256) void k_pv(const float* __restrict__ P,
                                            const float* __restrict__ Vm,
                                            float* __restrict__ Oa) {
    __shared__ float As[16 * 132];
    __shared__ float Bs[16 * 68];
    const int tid = threadIdx.x;
    const int q0 = blockIdx.x * 128, t0 = blockIdx.y * 64, nn = blockIdx.z;
    const float* A = P + nn * 262144;
    const float* B = Vm + nn * 131072;
    const int tx = tid & 15, ty = tid >> 4;
    float acc[8][4];
#pragma unroll
    for (int i = 0; i < 8; ++i)
#pragma unroll
        for (int j = 0; j < 4; ++j) acc[i][j] = 0.f;

    for (int kc = 0; kc < 512; kc += 16) {
#pragma unroll
        for (int l = 0; l < 2; ++l) {
            int s = tid + l * 256;
            int qq = s >> 2, tq = (s & 3) * 4;
            float4 v = F4(&A[(q0 + qq) * 512 + kc + tq]);
            As[(tq + 0) * 132 + qq] = v.x;
            As[(tq + 1) * 132 + qq] = v.y;
            As[(tq + 2) * 132 + qq] = v.z;
            As[(tq + 3) * 132 + qq] = v.w;
        }
#pragma unroll
        for (int l = 0; l < 4; ++l) {
            int e = tid + l * 256;
            int kk = e >> 6, tt = e & 63;
            Bs[kk * 68 + tt] = B[(kc + kk) * 256 + t0 + tt];
        }
        __syncthreads();
#pragma unroll
        for (int kk = 0; kk < 16; ++kk) {
            float4 a0 = F4(&As[kk * 132 + ty * 8]);
            float4 a1 = F4(&As[kk * 132 + ty * 8 + 4]);
            float4 b  = F4(&Bs[kk * 68 + tx * 4]);
            float av[8] = {a0.x, a0.y, a0.z, a0.w, a1.x, a1.y, a1.z, a1.w};
            float bv[4] = {b.x, b.y, b.z, b.w};
#pragma unroll
            for (int i = 0; i < 8; ++i)
#pragma unroll
                for (int j = 0; j < 4; ++j) acc[i][j] += av[i] * bv[j];
        }
        __syncthreads();
    }
    float* C = Oa + nn * 131072;
#pragma unroll
    for (int i = 0; i < 8; ++i)
        *(float4*)&C[(q0 + ty * 8 + i) * 256 + t0 + tx * 4] =
            make_float4(acc[i][0], acc[i][1], acc[i][2], acc[i][3]);
}

// ---- scatter PV result into Sa NCHW (4,512,8,256); coalesced writes ----
__global__ __launch_bounds__(256) void k_scatter_sa(const float* __restrict__ Oa,
                                                    float* __restrict__ Sa) {
    int o = blockIdx.x * 256 + threadIdx.x;     // 4194304 exact
    int w  = o & 255;
    int s2 = (o >> 8) & 7;
    int d2 = (o >> 11) & 511;
    int b2 = o >> 20;
    int nn = b2 * 8 + s2;
    int qp = (w >> 3) * 16 + (w & 7) * 2 + (d2 >> 8);
    int t  = (d2 & 7) * 32 + ((d2 >> 3) & 31);
    Sa[o] = Oa[(nn * 512 + qp) * 256 + t];
}

// ---------------------------------------------------------------------------
extern "C" void kernel_launch(void* const* d_in, const int* in_sizes, int n_in,
                              void* d_out, int out_size, void* d_ws, size_t ws_size,
                              hipStream_t stream) {
    const float* q  = (const float*)d_in[0];
    const float* k  = (const float*)d_in[1];
    const float* v  = (const float*)d_in[2];
    const float* Wq = (const float*)d_in[3];
    const float* bq = (const float*)d_in[4];
    const float* Wk = (const float*)d_in[5];
    const float* bk = (const float*)d_in[6];
    const float* Wv = (const float*)d_in[7];
    const float* bv = (const float*)d_in[8];
    const float* Wo = (const float*)d_in[9];
    const float* bo = (const float*)d_in[10];

    float* ws  = (float*)d_ws;
    float* WtQ = ws;
    float* WtK = WtQ + 2359296;
    float* WtV = WtK + 2359296;
    float* WtO = WtV + 2359296;
    float* Qm  = WtO + 2359296;
    float* Km  = Qm + 4194304;
    float* Vm  = Km + 4194304;
    float* Oa  = Qm;   // reuse: Qm dead after k_scores
    float* Sa  = Km;   // reuse: Km dead after k_scores
    // total ws use: 4*2359296 + 3*4194304 floats = 88.1 MB

    float* y_out = (float*)d_out;              // 4194304 floats
    float* attn  = y_out + 4194304;            // 8388608 floats

    k_transpose_w<<<9216, 256, 0, stream>>>(Wq, WtQ);
    k_transpose_w<<<9216, 256, 0, stream>>>(Wk, WtK);
    k_transpose_w<<<9216, 256, 0, stream>>>(Wv, WtV);
    k_transpose_w<<<9216, 256, 0, stream>>>(Wo, WtO);

    k_conv_qkv<<<dim3(64, 8), 256, 0, stream>>>(q, WtQ, bq, Qm);
    k_conv_qkv<<<dim3(64, 8), 256, 0, stream>>>(k, WtK, bk, Km);
    k_conv_qkv<<<dim3(64, 8), 256, 0, stream>>>(v, WtV, bv, Vm);

    k_scores<<<dim3(4, 8, 32), 256, 0, stream>>>(Qm, Km, attn);
    k_softmax<<<16384, 256, 0, stream>>>(attn);
    k_pv<<<dim3(4, 4, 32), 256, 0, stream>>>(attn, Vm, Oa);
    k_scatter_sa<<<16384, 256, 0, stream>>>(Oa, Sa);
    k_conv_o<<<dim3(64, 8), 256, 0, stream>>>(Sa, WtO, bo, y_out);
}

// Round 2
// 949.904 us; speedup vs baseline: 3.1943x; 3.1943x over previous
//
#include <hip/hip_runtime.h>

// ---------------------------------------------------------------------------
// MultiHeadAttention_60000693125780  — round 2: MFMA convs
//
// B=4,S=8,D=512,R=32,C=8,H=8,dep=1,f=3
// conv-qkv: 32 images, 512ch, 32x8 spatial  (M=8192, N=512, K=9*512=4608)
// conv-o  : 4  images, 512ch, 8x256 spatial (M=8192, N=512, K=4608)
//
// Convs = implicit GEMM on mfma_f32_16x16x32_bf16, 128x128 block tile, BK=32,
// global_load_lds 16B staging from padded-NHWC bf16 inputs (halo pre-zeroed)
// and W[co][k] bf16 weights. Q/K convs use split-bf16 (hi+lo, 3 MFMAs) so the
// softmax logits keep ~fp32 accuracy (logit std ~30, attn threshold 2%).
// Attention kernels (scores/softmax/pv) unchanged fp32 from round 1.
//
// Verified MFMA lane layouts (guide §3, m89/m91):
//   A[m=lane&15][k=(lane>>4)*8+j]   B[k=(lane>>4)*8+j][n=lane&15]
//   C/D: col=lane&15, row=(lane>>4)*4+reg
// ---------------------------------------------------------------------------

typedef __attribute__((ext_vector_type(8))) short short8;
typedef __attribute__((ext_vector_type(4))) float f32x4;

#define F4(p) (*(const float4*)(p))
#define MFMA16(a, b, c) __builtin_amdgcn_mfma_f32_16x16x32_bf16((a), (b), (c), 0, 0, 0)

__device__ __forceinline__ void gl_lds16(const void* g, void* l) {
    __builtin_amdgcn_global_load_lds(
        (const __attribute__((address_space(1))) unsigned int*)g,
        (__attribute__((address_space(3))) unsigned int*)l, 16, 0, 0);
}

__device__ __forceinline__ unsigned short f2bf(float f) {
    unsigned u = __float_as_uint(f);
    return (unsigned short)((u + 0x7fffu + ((u >> 16) & 1u)) >> 16);
}
__device__ __forceinline__ float bf2f(unsigned short h) {
    return __uint_as_float(((unsigned)h) << 16);
}

// ---- weights: W[co][ci][tap] fp32 -> Wh/Wl[co][tap*512+ci] bf16 ----
__global__ __launch_bounds__(256) void k_prep_w(const float* __restrict__ W,
                                                unsigned short* __restrict__ Wh,
                                                unsigned short* __restrict__ Wl) {
    unsigned tid = blockIdx.x * 256 + threadIdx.x;      // 512*4608 exact
    unsigned ci  = tid & 511;
    unsigned tap = (tid >> 9) % 9u;
    unsigned co  = tid / 4608u;
    float wv = W[(co * 512 + ci) * 9 + tap];
    unsigned short h = f2bf(wv);
    Wh[tid] = h;
    if (Wl) Wl[tid] = f2bf(wv - bf2f(h));
}

// ---- qkv input: NCHW fp32 (32,512,32,8) -> padded NHWC bf16 [32][34][10][512]
__global__ __launch_bounds__(256) void k_prep_x(const float* __restrict__ X,
                                                unsigned short* __restrict__ Xh,
                                                unsigned short* __restrict__ Xl) {
    unsigned o = blockIdx.x * 256 + threadIdx.x;        // 32*34*10*512 exact
    unsigned ci = o & 511;
    unsigned u  = o >> 9;
    unsigned xx = u % 10u; u /= 10u;
    unsigned yy = u % 34u;
    unsigned n  = u / 34u;
    float v = 0.f;
    if (xx >= 1 && xx <= 8 && yy >= 1 && yy <= 32)
        v = X[(n * 512 + ci) * 256 + (yy - 1) * 8 + (xx - 1)];
    unsigned short h = f2bf(v);
    Xh[o] = h;
    if (Xl) Xl[o] = f2bf(v - bf2f(h));
}

// ---- PV output -> padded NHWC bf16 [4][10][258][512] for conv_o ----
__global__ __launch_bounds__(256) void k_prep_sp(const float* __restrict__ Oa,
                                                 unsigned short* __restrict__ Sp) {
    unsigned o = blockIdx.x * 256 + threadIdx.x;        // 4*10*258*512 exact
    unsigned ci = o & 511;
    unsigned u  = o >> 9;
    unsigned xx = u % 258u; u /= 258u;
    unsigned yy = u % 10u;
    unsigned b2 = u / 10u;
    float v = 0.f;
    if (xx >= 1 && xx <= 256 && yy >= 1 && yy <= 8) {
        unsigned ww = xx - 1, s2 = yy - 1, d2 = ci;
        unsigned nn = b2 * 8 + s2;
        unsigned qp = (ww >> 3) * 16 + (ww & 7) * 2 + (d2 >> 8);
        unsigned t  = (d2 & 7) * 32 + ((d2 >> 3) & 31);
        v = Oa[(nn * 512 + qp) * 256 + t];
    }
    Sp[o] = f2bf(v);
}

// ---- split-bf16 MFMA conv (qkv geometry), epilogue -> Qm[nn][dd][t] fp32 ----
__global__ __launch_bounds__(256) void k_conv_qkv_split(
        const unsigned short* __restrict__ Xh, const unsigned short* __restrict__ Xl,
        const unsigned short* __restrict__ Wh, const unsigned short* __restrict__ Wl,
        const float* __restrict__ bias, float* __restrict__ Qm) {
    __shared__ __align__(16) short Ah[4096], Al[4096], Bh[4096], Bl[4096];
    const int tid = threadIdx.x;
    const int w = tid >> 6, l = tid & 63;
    const int n   = blockIdx.x >> 1;
    const int p0  = (blockIdx.x & 1) * 128;
    const int co0 = blockIdx.y * 128;
    const int lm = l & 15, lq = l >> 4;

    int arow[2], brow[2];
#pragma unroll
    for (int i = 0; i < 2; ++i) {
        int r  = w * 32 + i * 16 + (l >> 2);
        int px = p0 + r;
        int y = px >> 3, x = px & 7;
        arow[i] = ((n * 34 + y + 1) * 10 + (x + 1)) * 512 + (l & 3) * 8;
        brow[i] = (co0 + r) * 4608 + (l & 3) * 8;
    }
    const int lds0 = w * 2048;          // byte offsets, wave-uniform
    const int lds1 = w * 2048 + 1024;

    f32x4 acc[4][4];
#pragma unroll
    for (int ni = 0; ni < 4; ++ni) {
        float b = bias[co0 + (w >> 1) * 64 + ni * 16 + lm];
#pragma unroll
        for (int mi = 0; mi < 4; ++mi) acc[mi][ni] = (f32x4){b, b, b, b};
    }

    for (int tap = 0; tap < 9; ++tap) {
        const int tapoff = ((tap / 3 - 1) * 10 + (tap % 3 - 1)) * 512;
        const int wb = tap * 512;
        for (int ci0 = 0; ci0 < 512; ci0 += 32) {
            {
                int a0 = arow[0] + tapoff + ci0, a1 = arow[1] + tapoff + ci0;
                int b0 = brow[0] + wb + ci0,     b1 = brow[1] + wb + ci0;
                gl_lds16(Xh + a0, (char*)Ah + lds0);
                gl_lds16(Xh + a1, (char*)Ah + lds1);
                gl_lds16(Xl + a0, (char*)Al + lds0);
                gl_lds16(Xl + a1, (char*)Al + lds1);
                gl_lds16(Wh + b0, (char*)Bh + lds0);
                gl_lds16(Wh + b1, (char*)Bh + lds1);
                gl_lds16(Wl + b0, (char*)Bl + lds0);
                gl_lds16(Wl + b1, (char*)Bl + lds1);
            }
            __syncthreads();
            short8 ah[4], al[4], bh[4], bl[4];
#pragma unroll
            for (int mi = 0; mi < 4; ++mi) {
                int row = (w & 1) * 64 + mi * 16 + lm;
                ah[mi] = *(const short8*)&Ah[row * 32 + lq * 8];
                al[mi] = *(const short8*)&Al[row * 32 + lq * 8];
            }
#pragma unroll
            for (int ni = 0; ni < 4; ++ni) {
                int row = (w >> 1) * 64 + ni * 16 + lm;
                bh[ni] = *(const short8*)&Bh[row * 32 + lq * 8];
                bl[ni] = *(const short8*)&Bl[row * 32 + lq * 8];
            }
#pragma unroll
            for (int mi = 0; mi < 4; ++mi)
#pragma unroll
                for (int ni = 0; ni < 4; ++ni) {
                    acc[mi][ni] = MFMA16(al[mi], bh[ni], acc[mi][ni]);
                    acc[mi][ni] = MFMA16(ah[mi], bl[ni], acc[mi][ni]);
                    acc[mi][ni] = MFMA16(ah[mi], bh[ni], acc[mi][ni]);
                }
            __syncthreads();
        }
    }

    const int h = n >> 2, nl = n & 3;
    const int pxbase = p0 + (w & 1) * 64 + lq * 4;
    const int x0q = pxbase & 7;
#pragma unroll
    for (int mi = 0; mi < 4; ++mi) {
        int px = pxbase + mi * 16;
        int y = px >> 3;
#pragma unroll
        for (int ni = 0; ni < 4; ++ni) {
            int co = co0 + (w >> 1) * 64 + ni * 16 + lm;
            int nn = nl * 8 + (co >> 6);
            int dd = (co & 63) * 8 + (y >> 2);
            int t0 = h * 32 + (y & 3) * 8 + x0q;
            *(f32x4*)&Qm[(nn * 512 + dd) * 256 + t0] = acc[mi][ni];
        }
    }
}

// ---- plain bf16 MFMA conv (qkv geometry), epilogue -> Vm[nn][dd][t] fp32 ----
__global__ __launch_bounds__(256) void k_conv_qkv_plain(
        const unsigned short* __restrict__ Xh, const unsigned short* __restrict__ Wh,
        const float* __restrict__ bias, float* __restrict__ Vm) {
    __shared__ __align__(16) short Ah[4096], Bh[4096];
    const int tid = threadIdx.x;
    const int w = tid >> 6, l = tid & 63;
    const int n   = blockIdx.x >> 1;
    const int p0  = (blockIdx.x & 1) * 128;
    const int co0 = blockIdx.y * 128;
    const int lm = l & 15, lq = l >> 4;

    int arow[2], brow[2];
#pragma unroll
    for (int i = 0; i < 2; ++i) {
        int r  = w * 32 + i * 16 + (l >> 2);
        int px = p0 + r;
        int y = px >> 3, x = px & 7;
        arow[i] = ((n * 34 + y + 1) * 10 + (x + 1)) * 512 + (l & 3) * 8;
        brow[i] = (co0 + r) * 4608 + (l & 3) * 8;
    }
    const int lds0 = w * 2048, lds1 = w * 2048 + 1024;

    f32x4 acc[4][4];
#pragma unroll
    for (int ni = 0; ni < 4; ++ni) {
        float b = bias[co0 + (w >> 1) * 64 + ni * 16 + lm];
#pragma unroll
        for (int mi = 0; mi < 4; ++mi) acc[mi][ni] = (f32x4){b, b, b, b};
    }

    for (int tap = 0; tap < 9; ++tap) {
        const int tapoff = ((tap / 3 - 1) * 10 + (tap % 3 - 1)) * 512;
        const int wb = tap * 512;
        for (int ci0 = 0; ci0 < 512; ci0 += 32) {
            {
                int a0 = arow[0] + tapoff + ci0, a1 = arow[1] + tapoff + ci0;
                int b0 = brow[0] + wb + ci0,     b1 = brow[1] + wb + ci0;
                gl_lds16(Xh + a0, (char*)Ah + lds0);
                gl_lds16(Xh + a1, (char*)Ah + lds1);
                gl_lds16(Wh + b0, (char*)Bh + lds0);
                gl_lds16(Wh + b1, (char*)Bh + lds1);
            }
            __syncthreads();
            short8 af[4], bf[4];
#pragma unroll
            for (int mi = 0; mi < 4; ++mi)
                af[mi] = *(const short8*)&Ah[((w & 1) * 64 + mi * 16 + lm) * 32 + lq * 8];
#pragma unroll
            for (int ni = 0; ni < 4; ++ni)
                bf[ni] = *(const short8*)&Bh[((w >> 1) * 64 + ni * 16 + lm) * 32 + lq * 8];
#pragma unroll
            for (int mi = 0; mi < 4; ++mi)
#pragma unroll
                for (int ni = 0; ni < 4; ++ni)
                    acc[mi][ni] = MFMA16(af[mi], bf[ni], acc[mi][ni]);
            __syncthreads();
        }
    }

    const int h = n >> 2, nl = n & 3;
    const int pxbase = p0 + (w & 1) * 64 + lq * 4;
    const int x0q = pxbase & 7;
#pragma unroll
    for (int mi = 0; mi < 4; ++mi) {
        int px = pxbase + mi * 16;
        int y = px >> 3;
#pragma unroll
        for (int ni = 0; ni < 4; ++ni) {
            int co = co0 + (w >> 1) * 64 + ni * 16 + lm;
            int nn = nl * 8 + (co >> 6);
            int dd = (co & 63) * 8 + (y >> 2);
            int t0 = h * 32 + (y & 3) * 8 + x0q;
            *(f32x4*)&Vm[(nn * 512 + dd) * 256 + t0] = acc[mi][ni];
        }
    }
}

// ---- plain bf16 MFMA conv (o geometry), epilogue -> Y NCHW fp32 ----
__global__ __launch_bounds__(256) void k_conv_o_mfma(
        const unsigned short* __restrict__ Sp, const unsigned short* __restrict__ Wh,
        const float* __restrict__ bias, float* __restrict__ Y) {
    __shared__ __align__(16) short Ah[4096], Bh[4096];
    const int tid = threadIdx.x;
    const int w = tid >> 6, l = tid & 63;
    const int n   = blockIdx.x >> 4;
    const int yy  = (blockIdx.x >> 1) & 7;
    const int x0  = (blockIdx.x & 1) * 128;
    const int co0 = blockIdx.y * 128;
    const int lm = l & 15, lq = l >> 4;

    int arow[2], brow[2];
#pragma unroll
    for (int i = 0; i < 2; ++i) {
        int r = w * 32 + i * 16 + (l >> 2);
        arow[i] = ((n * 10 + yy + 1) * 258 + (x0 + r + 1)) * 512 + (l & 3) * 8;
        brow[i] = (co0 + r) * 4608 + (l & 3) * 8;
    }
    const int lds0 = w * 2048, lds1 = w * 2048 + 1024;

    f32x4 acc[4][4];
#pragma unroll
    for (int ni = 0; ni < 4; ++ni) {
        float b = bias[co0 + (w >> 1) * 64 + ni * 16 + lm];
#pragma unroll
        for (int mi = 0; mi < 4; ++mi) acc[mi][ni] = (f32x4){b, b, b, b};
    }

    for (int tap = 0; tap < 9; ++tap) {
        const int tapoff = ((tap / 3 - 1) * 258 + (tap % 3 - 1)) * 512;
        const int wb = tap * 512;
        for (int ci0 = 0; ci0 < 512; ci0 += 32) {
            {
                int a0 = arow[0] + tapoff + ci0, a1 = arow[1] + tapoff + ci0;
                int b0 = brow[0] + wb + ci0,     b1 = brow[1] + wb + ci0;
                gl_lds16(Sp + a0, (char*)Ah + lds0);
                gl_lds16(Sp + a1, (char*)Ah + lds1);
                gl_lds16(Wh + b0, (char*)Bh + lds0);
                gl_lds16(Wh + b1, (char*)Bh + lds1);
            }
            __syncthreads();
            short8 af[4], bf[4];
#pragma unroll
            for (int mi = 0; mi < 4; ++mi)
                af[mi] = *(const short8*)&Ah[((w & 1) * 64 + mi * 16 + lm) * 32 + lq * 8];
#pragma unroll
            for (int ni = 0; ni < 4; ++ni)
                bf[ni] = *(const short8*)&Bh[((w >> 1) * 64 + ni * 16 + lm) * 32 + lq * 8];
#pragma unroll
            for (int mi = 0; mi < 4; ++mi)
#pragma unroll
                for (int ni = 0; ni < 4; ++ni)
                    acc[mi][ni] = MFMA16(af[mi], bf[ni], acc[mi][ni]);
            __syncthreads();
        }
    }

    const int pxb = x0 + (w & 1) * 64 + lq * 4;
#pragma unroll
    for (int mi = 0; mi < 4; ++mi) {
        int px = pxb + mi * 16;
#pragma unroll
        for (int ni = 0; ni < 4; ++ni) {
            int co = co0 + (w >> 1) * 64 + ni * 16 + lm;
            *(f32x4*)&Y[n * 1048576 + co * 2048 + yy * 256 + px] = acc[mi][ni];
        }
    }
}

// ======================= attention (unchanged fp32, round 1) ================
__global__ __launch_bounds__(256) void k_scores(const float* __restrict__ Qm,
                                                const float* __restrict__ Km,
                                                float* __restrict__ Sc) {
    __shared__ float As[16 * 132];
    __shared__ float Bs[16 * 68];
    const int tid = threadIdx.x;
    const int q0 = blockIdx.x * 128, k0 = blockIdx.y * 64, nn = blockIdx.z;
    const float* A = Qm + nn * 131072;
    const float* B = Km + nn * 131072;
    const int tx = tid & 15, ty = tid >> 4;
    float acc[8][4];
#pragma unroll
    for (int i = 0; i < 8; ++i)
#pragma unroll
        for (int j = 0; j < 4; ++j) acc[i][j] = 0.f;

    for (int t0 = 0; t0 < 256; t0 += 16) {
#pragma unroll
        for (int l = 0; l < 2; ++l) {
            int s = tid + l * 256;
            int qq = s >> 2, tq = (s & 3) * 4;
            float4 v = F4(&A[(q0 + qq) * 256 + t0 + tq]);
            As[(tq + 0) * 132 + qq] = v.x;
            As[(tq + 1) * 132 + qq] = v.y;
            As[(tq + 2) * 132 + qq] = v.z;
            As[(tq + 3) * 132 + qq] = v.w;
        }
        {
            int cc = tid >> 2, tq = (tid & 3) * 4;
            float4 v = F4(&B[(k0 + cc) * 256 + t0 + tq]);
            Bs[(tq + 0) * 68 + cc] = v.x;
            Bs[(tq + 1) * 68 + cc] = v.y;
            Bs[(tq + 2) * 68 + cc] = v.z;
            Bs[(tq + 3) * 68 + cc] = v.w;
        }
        __syncthreads();
#pragma unroll
        for (int kk = 0; kk < 16; ++kk) {
            float4 a0 = F4(&As[kk * 132 + ty * 8]);
            float4 a1 = F4(&As[kk * 132 + ty * 8 + 4]);
            float4 b  = F4(&Bs[kk * 68 + tx * 4]);
            float av[8] = {a0.x, a0.y, a0.z, a0.w, a1.x, a1.y, a1.z, a1.w};
            float bv[4] = {b.x, b.y, b.z, b.w};
#pragma unroll
            for (int i = 0; i < 8; ++i)
#pragma unroll
                for (int j = 0; j < 4; ++j) acc[i][j] += av[i] * bv[j];
        }
        __syncthreads();
    }
    float* C = Sc + nn * 262144;
#pragma unroll
    for (int i = 0; i < 8; ++i)
        *(float4*)&C[(q0 + ty * 8 + i) * 512 + k0 + tx * 4] =
            make_float4(acc[i][0], acc[i][1], acc[i][2], acc[i][3]);
}

__global__ __launch_bounds__(256) void k_softmax(float* __restrict__ Sc) {
    __shared__ float red[8];
    float* p = Sc + (size_t)blockIdx.x * 512;
    const int tid = threadIdx.x;
    float x0 = p[tid], x1 = p[tid + 256];
    float m = fmaxf(x0, x1);
#pragma unroll
    for (int off = 32; off; off >>= 1) m = fmaxf(m, __shfl_xor(m, off));
    if ((tid & 63) == 0) red[tid >> 6] = m;
    __syncthreads();
    m = fmaxf(fmaxf(red[0], red[1]), fmaxf(red[2], red[3]));
    float e0 = __expf(x0 - m), e1 = __expf(x1 - m);
    float s = e0 + e1;
#pragma unroll
    for (int off = 32; off; off >>= 1) s += __shfl_xor(s, off);
    if ((tid & 63) == 0) red[4 + (tid >> 6)] = s;
    __syncthreads();
    s = red[4] + red[5] + red[6] + red[7];
    float inv = 1.0f / s;
    p[tid] = e0 * inv;
    p[tid + 256] = e1 * inv;
}

__global__ __launch_bounds__(256) void k_pv(const float* __restrict__ P,
                                            const float* __restrict__ Vm,
                                            float* __restrict__ Oa) {
    __shared__ float As[16 * 132];
    __shared__ float Bs[16 * 68];
    const int tid = threadIdx.x;
    const int q0 = blockIdx.x * 128, t0 = blockIdx.y * 64, nn = blockIdx.z;
    const float* A = P + nn * 262144;
    const float* B = Vm + nn * 131072;
    const int tx = tid & 15, ty = tid >> 4;
    float acc[8][4];
#pragma unroll
    for (int i = 0; i < 8; ++i)
#pragma unroll
        for (int j = 0; j < 4; ++j) acc[i][j] = 0.f;

    for (int kc = 0; kc < 512; kc += 16) {
#pragma unroll
        for (int l = 0; l < 2; ++l) {
            int s = tid + l * 256;
            int qq = s >> 2, tq = (s & 3) * 4;
            float4 v = F4(&A[(q0 + qq) * 512 + kc + tq]);
            As[(tq + 0) * 132 + qq] = v.x;
            As[(tq + 1) * 132 + qq] = v.y;
            As[(tq + 2) * 132 + qq] = v.z;
            As[(tq + 3) * 132 + qq] = v.w;
        }
#pragma unroll
        for (int l = 0; l < 4; ++l) {
            int e = tid + l * 256;
            int kk = e >> 6, tt = e & 63;
            Bs[kk * 68 + tt] = B[(kc + kk) * 256 + t0 + tt];
        }
        __syncthreads();
#pragma unroll
        for (int kk = 0; kk < 16; ++kk) {
            float4 a0 = F4(&As[kk * 132 + ty * 8]);
            float4 a1 = F4(&As[kk * 132 + ty * 8 + 4]);
            float4 b  = F4(&Bs[kk * 68 + tx * 4]);
            float av[8] = {a0.x, a0.y, a0.z, a0.w, a1.x, a1.y, a1.z, a1.w};
            float bv[4] = {b.x, b.y, b.z, b.w};
#pragma unroll
            for (int i = 0; i < 8; ++i)
#pragma unroll
                for (int j = 0; j < 4; ++j) acc[i][j] += av[i] * bv[j];
        }
        __syncthreads();
    }
    float* C = Oa + nn * 131072;
#pragma unroll
    for (int i = 0; i < 8; ++i)
        *(float4*)&C[(q0 + ty * 8 + i) * 256 + t0 + tx * 4] =
            make_float4(acc[i][0], acc[i][1], acc[i][2], acc[i][3]);
}

// ---------------------------------------------------------------------------
extern "C" void kernel_launch(void* const* d_in, const int* in_sizes, int n_in,
                              void* d_out, int out_size, void* d_ws, size_t ws_size,
                              hipStream_t stream) {
    const float* q  = (const float*)d_in[0];
    const float* k  = (const float*)d_in[1];
    const float* v  = (const float*)d_in[2];
    const float* Wq = (const float*)d_in[3];
    const float* bq = (const float*)d_in[4];
    const float* Wk = (const float*)d_in[5];
    const float* bk = (const float*)d_in[6];
    const float* Wv = (const float*)d_in[7];
    const float* bv = (const float*)d_in[8];
    const float* Wo = (const float*)d_in[9];
    const float* bo = (const float*)d_in[10];

    unsigned short* Wh = (unsigned short*)d_ws;          // 2359296
    unsigned short* Wl = Wh + 2359296;                   // 2359296
    unsigned short* Xh = Wl + 2359296;                   // 5570560
    unsigned short* Xl = Xh + 5570560;                   // 5570560
    float* Qm = (float*)(Xl + 5570560);                  // 4194304
    float* Km = Qm + 4194304;                            // 4194304
    float* Vm = Km + 4194304;                            // 4194304
    float* Oa = Qm;                                      // reuse (Qm dead after scores)
    unsigned short* Sp = Xh;                             // reuse (5283840 <= 5570560)
    // ws use: 2*(2*2359296 + 2*5570560) + 4*3*4194304 = 82.1 MB

    float* y_out = (float*)d_out;                        // 4194304 floats
    float* attn  = y_out + 4194304;                      // 8388608 floats

    // Q
    k_prep_w<<<9216, 256, 0, stream>>>(Wq, Wh, Wl);
    k_prep_x<<<21760, 256, 0, stream>>>(q, Xh, Xl);
    k_conv_qkv_split<<<dim3(64, 4), 256, 0, stream>>>(Xh, Xl, Wh, Wl, bq, Qm);
    // K
    k_prep_w<<<9216, 256, 0, stream>>>(Wk, Wh, Wl);
    k_prep_x<<<21760, 256, 0, stream>>>(k, Xh, Xl);
    k_conv_qkv_split<<<dim3(64, 4), 256, 0, stream>>>(Xh, Xl, Wh, Wl, bk, Km);
    // V (plain bf16)
    k_prep_w<<<9216, 256, 0, stream>>>(Wv, Wh, nullptr);
    k_prep_x<<<21760, 256, 0, stream>>>(v, Xh, nullptr);
    k_conv_qkv_plain<<<dim3(64, 4), 256, 0, stream>>>(Xh, Wh, bv, Vm);
    // attention (fp32)
    k_scores<<<dim3(4, 8, 32), 256, 0, stream>>>(Qm, Km, attn);
    k_softmax<<<16384, 256, 0, stream>>>(attn);
    k_pv<<<dim3(4, 4, 32), 256, 0, stream>>>(attn, Vm, Oa);
    // O conv (plain bf16)
    k_prep_w<<<9216, 256, 0, stream>>>(Wo, Wh, nullptr);
    k_prep_sp<<<20640, 256, 0, stream>>>(Oa, Sp);
    k_conv_o_mfma<<<dim3(64, 4), 256, 0, stream>>>(Sp, Wh, bo, y_out);
}

// Round 3
// 589.586 us; speedup vs baseline: 5.1465x; 1.6111x over previous
//
#include <hip/hip_runtime.h>

// ---------------------------------------------------------------------------
// MultiHeadAttention_60000693125780 — round 3
// All GEMM-shaped work on mfma_f32_16x16x32_bf16.
//  * merged Q/K/V conv: grid (64,4,3) = 768 blocks (~3/CU) — fixes 1-block/CU
//  * XOR bank-swizzle on LDS tiles (conflict-free b128 reads)
//  * scores = split-bf16 MFMA, pv = bf16 MFMA
//  * d_out regions used as scratch for prepped inputs before they're written
// Layouts:
//  Qh/Ql,Kh/Kl: [nn][dd][t] bf16 hi/lo   Vt: [nn][t][dd] bf16
//  Ph: [nn][q][k'] bf16   Oa: [nn][q][t] fp32   Sp: padded NHWC bf16
// ---------------------------------------------------------------------------

typedef __attribute__((ext_vector_type(8))) short short8;
typedef __attribute__((ext_vector_type(4))) float f32x4;
typedef __attribute__((ext_vector_type(4))) short short4v;

#define MFMA16(a, b, c) __builtin_amdgcn_mfma_f32_16x16x32_bf16((a), (b), (c), 0, 0, 0)

__device__ __forceinline__ void gl_lds16(const void* g, void* l) {
    __builtin_amdgcn_global_load_lds(
        (const __attribute__((address_space(1))) unsigned int*)g,
        (__attribute__((address_space(3))) unsigned int*)l, 16, 0, 0);
}
__device__ __forceinline__ unsigned short f2bf(float f) {
    unsigned u = __float_as_uint(f);
    return (unsigned short)((u + 0x7fffu + ((u >> 16) & 1u)) >> 16);
}
__device__ __forceinline__ float bf2f(unsigned short h) {
    return __uint_as_float(((unsigned)h) << 16);
}

// ---- weights: W[co][ci][tap] fp32 -> [co][tap*512+ci] bf16 (hi, optional lo)
__global__ __launch_bounds__(256) void k_prep_w_all(
        const float* __restrict__ Wq, const float* __restrict__ Wk,
        const float* __restrict__ Wv, const float* __restrict__ Wo,
        unsigned short* __restrict__ Wqh, unsigned short* __restrict__ Wql,
        unsigned short* __restrict__ Wkh, unsigned short* __restrict__ Wkl,
        unsigned short* __restrict__ Wvh, unsigned short* __restrict__ Woh) {
    int z = blockIdx.y;
    const float* W = z == 0 ? Wq : z == 1 ? Wk : z == 2 ? Wv : Wo;
    unsigned short* Wh = z == 0 ? Wqh : z == 1 ? Wkh : z == 2 ? Wvh : Woh;
    unsigned short* Wl = z == 0 ? Wql : z == 1 ? Wkl : nullptr;
    unsigned tid = blockIdx.x * 256 + threadIdx.x;      // 512*4608 exact
    unsigned ci  = tid & 511;
    unsigned tap = (tid >> 9) % 9u;
    unsigned co  = tid / 4608u;
    float wv = W[(co * 512 + ci) * 9 + tap];
    unsigned short h = f2bf(wv);
    Wh[tid] = h;
    if (Wl) Wl[tid] = f2bf(wv - bf2f(h));
}

// ---- inputs: NCHW fp32 (32,512,32,8) -> padded NHWC bf16 [32][34][10][512]
__global__ __launch_bounds__(256) void k_prep_x_all(
        const float* __restrict__ q, const float* __restrict__ k,
        const float* __restrict__ v,
        unsigned short* __restrict__ Xqh, unsigned short* __restrict__ Xql,
        unsigned short* __restrict__ Xkh, unsigned short* __restrict__ Xkl,
        unsigned short* __restrict__ Xvh) {
    int z = blockIdx.y;
    const float* X = z == 0 ? q : z == 1 ? k : v;
    unsigned short* Xh = z == 0 ? Xqh : z == 1 ? Xkh : Xvh;
    unsigned short* Xl = z == 0 ? Xql : z == 1 ? Xkl : nullptr;
    unsigned o = blockIdx.x * 256 + threadIdx.x;        // 32*34*10*512 exact
    unsigned ci = o & 511;
    unsigned u  = o >> 9;
    unsigned xx = u % 10u; u /= 10u;
    unsigned yy = u % 34u;
    unsigned n  = u / 34u;
    float val = 0.f;
    if (xx >= 1 && xx <= 8 && yy >= 1 && yy <= 32)
        val = X[(n * 512 + ci) * 256 + (yy - 1) * 8 + (xx - 1)];
    unsigned short h = f2bf(val);
    Xh[o] = h;
    if (Xl) Xl[o] = f2bf(val - bf2f(h));
}

// ---- merged QKV conv: z=0 Q(split), z=1 K(split), z=2 V(plain, ->Vt) ----
__global__ __launch_bounds__(256) void k_conv_qkv_all(
        const unsigned short* __restrict__ Xqh, const unsigned short* __restrict__ Xql,
        const unsigned short* __restrict__ Xkh, const unsigned short* __restrict__ Xkl,
        const unsigned short* __restrict__ Xvh,
        const unsigned short* __restrict__ Wqh_, const unsigned short* __restrict__ Wql_,
        const unsigned short* __restrict__ Wkh_, const unsigned short* __restrict__ Wkl_,
        const unsigned short* __restrict__ Wvh_,
        const float* __restrict__ bq, const float* __restrict__ bk,
        const float* __restrict__ bv,
        unsigned short* __restrict__ Qh, unsigned short* __restrict__ Ql,
        unsigned short* __restrict__ Kh, unsigned short* __restrict__ Kl,
        unsigned short* __restrict__ Vt) {
    __shared__ __align__(16) short Ah[4096], Al[4096], Bh[4096], Bl[4096];
    const int z = blockIdx.z;
    const bool split = (z < 2);
    const unsigned short* Xh = z == 0 ? Xqh : z == 1 ? Xkh : Xvh;
    const unsigned short* Xl = z == 0 ? Xql : Xkl;
    const unsigned short* Wh = z == 0 ? Wqh_ : z == 1 ? Wkh_ : Wvh_;
    const unsigned short* Wl = z == 0 ? Wql_ : Wkl_;
    const float* bias = z == 0 ? bq : z == 1 ? bk : bv;
    unsigned short* Oh = z == 0 ? Qh : Kh;
    unsigned short* Ol = z == 0 ? Ql : Kl;

    const int tid = threadIdx.x;
    const int w = tid >> 6, l = tid & 63;
    const int n   = blockIdx.x >> 1;
    const int p0  = (blockIdx.x & 1) * 128;
    const int co0 = blockIdx.y * 128;
    const int lm = l & 15, lq = l >> 4;

    int arow[2], brow[2];
#pragma unroll
    for (int i = 0; i < 2; ++i) {
        int rr = w * 32 + i * 16 + (l >> 2);
        int c  = (l & 3) ^ ((rr >> 1) & 3);             // XOR bank swizzle
        int px = p0 + rr;
        int y = px >> 3, x = px & 7;
        arow[i] = ((n * 34 + y + 1) * 10 + (x + 1)) * 512 + c * 8;
        brow[i] = (co0 + rr) * 4608 + c * 8;
    }
    const int lds0 = w * 2048, lds1 = w * 2048 + 1024;

    int aoff[4], boff[4];
#pragma unroll
    for (int mi = 0; mi < 4; ++mi) {
        int row = (w & 1) * 64 + mi * 16 + lm;
        aoff[mi] = row * 32 + (lq ^ ((row >> 1) & 3)) * 8;
    }
#pragma unroll
    for (int ni = 0; ni < 4; ++ni) {
        int row = (w >> 1) * 64 + ni * 16 + lm;
        boff[ni] = row * 32 + (lq ^ ((row >> 1) & 3)) * 8;
    }

    f32x4 acc[4][4];
#pragma unroll
    for (int ni = 0; ni < 4; ++ni) {
        float b = bias[co0 + (w >> 1) * 64 + ni * 16 + lm];
#pragma unroll
        for (int mi = 0; mi < 4; ++mi) acc[mi][ni] = (f32x4){b, b, b, b};
    }

    for (int tap = 0; tap < 9; ++tap) {
        const int tapoff = ((tap / 3 - 1) * 10 + (tap % 3 - 1)) * 512;
        const int wb = tap * 512;
        for (int ci0 = 0; ci0 < 512; ci0 += 32) {
            int a0 = arow[0] + tapoff + ci0, a1 = arow[1] + tapoff + ci0;
            int b0 = brow[0] + wb + ci0,     b1 = brow[1] + wb + ci0;
            gl_lds16(Xh + a0, (char*)Ah + lds0);
            gl_lds16(Xh + a1, (char*)Ah + lds1);
            gl_lds16(Wh + b0, (char*)Bh + lds0);
            gl_lds16(Wh + b1, (char*)Bh + lds1);
            if (split) {
                gl_lds16(Xl + a0, (char*)Al + lds0);
                gl_lds16(Xl + a1, (char*)Al + lds1);
                gl_lds16(Wl + b0, (char*)Bl + lds0);
                gl_lds16(Wl + b1, (char*)Bl + lds1);
            }
            __syncthreads();
            short8 ah[4], bh[4];
#pragma unroll
            for (int mi = 0; mi < 4; ++mi) ah[mi] = *(const short8*)&Ah[aoff[mi]];
#pragma unroll
            for (int ni = 0; ni < 4; ++ni) bh[ni] = *(const short8*)&Bh[boff[ni]];
#pragma unroll
            for (int mi = 0; mi < 4; ++mi)
#pragma unroll
                for (int ni = 0; ni < 4; ++ni)
                    acc[mi][ni] = MFMA16(ah[mi], bh[ni], acc[mi][ni]);
            if (split) {
                short8 alv[4], blv[4];
#pragma unroll
                for (int mi = 0; mi < 4; ++mi) alv[mi] = *(const short8*)&Al[aoff[mi]];
#pragma unroll
                for (int mi = 0; mi < 4; ++mi)
#pragma unroll
                    for (int ni = 0; ni < 4; ++ni)
                        acc[mi][ni] = MFMA16(alv[mi], bh[ni], acc[mi][ni]);
#pragma unroll
                for (int ni = 0; ni < 4; ++ni) blv[ni] = *(const short8*)&Bl[boff[ni]];
#pragma unroll
                for (int mi = 0; mi < 4; ++mi)
#pragma unroll
                    for (int ni = 0; ni < 4; ++ni)
                        acc[mi][ni] = MFMA16(ah[mi], blv[ni], acc[mi][ni]);
            }
            __syncthreads();
        }
    }

    const int hh = n >> 2, nl = n & 3;
    const int pxbase = p0 + (w & 1) * 64 + lq * 4;
    const int x0q = pxbase & 7;
#pragma unroll
    for (int mi = 0; mi < 4; ++mi) {
        int px = pxbase + mi * 16;
        int y = px >> 3;
#pragma unroll
        for (int ni = 0; ni < 4; ++ni) {
            int co = co0 + (w >> 1) * 64 + ni * 16 + lm;
            int nn = nl * 8 + (co >> 6);
            int dd = (co & 63) * 8 + (y >> 2);
            int t0 = hh * 32 + (y & 3) * 8 + x0q;
            if (split) {
                short4v hv, lv;
#pragma unroll
                for (int r = 0; r < 4; ++r) {
                    float xv = acc[mi][ni][r];
                    unsigned short hb = f2bf(xv);
                    hv[r] = (short)hb;
                    lv[r] = (short)f2bf(xv - bf2f(hb));
                }
                int base = (nn * 512 + dd) * 256 + t0;
                *(short4v*)&Oh[base] = hv;
                *(short4v*)&Ol[base] = lv;
            } else {
#pragma unroll
                for (int r = 0; r < 4; ++r)
                    Vt[(nn * 256 + t0 + r) * 512 + dd] = f2bf(acc[mi][ni][r]);
            }
        }
    }
}

// ---- scores: Sc[nn][q][k'] fp32 via split-bf16 MFMA (K=256) ----
__global__ __launch_bounds__(256) void k_scores_mfma(
        const unsigned short* __restrict__ Qh, const unsigned short* __restrict__ Ql,
        const unsigned short* __restrict__ Kh, const unsigned short* __restrict__ Kl,
        float* __restrict__ Sc) {
    __shared__ __align__(16) short Ah[4096], Al[4096], Bh[4096], Bl[4096];
    const int tid = threadIdx.x;
    const int w = tid >> 6, l = tid & 63;
    const int q0 = blockIdx.x * 128, k0 = blockIdx.y * 128, nn = blockIdx.z;
    const int lm = l & 15, lq = l >> 4;

    int arow[2], brow[2];
#pragma unroll
    for (int i = 0; i < 2; ++i) {
        int rr = w * 32 + i * 16 + (l >> 2);
        int c  = (l & 3) ^ ((rr >> 1) & 3);
        arow[i] = (nn * 512 + q0 + rr) * 256 + c * 8;
        brow[i] = (nn * 512 + k0 + rr) * 256 + c * 8;
    }
    const int lds0 = w * 2048, lds1 = w * 2048 + 1024;

    int aoff[4], boff[4];
#pragma unroll
    for (int mi = 0; mi < 4; ++mi) {
        int row = (w & 1) * 64 + mi * 16 + lm;
        aoff[mi] = row * 32 + (lq ^ ((row >> 1) & 3)) * 8;
    }
#pragma unroll
    for (int ni = 0; ni < 4; ++ni) {
        int row = (w >> 1) * 64 + ni * 16 + lm;
        boff[ni] = row * 32 + (lq ^ ((row >> 1) & 3)) * 8;
    }

    f32x4 acc[4][4];
#pragma unroll
    for (int mi = 0; mi < 4; ++mi)
#pragma unroll
        for (int ni = 0; ni < 4; ++ni) acc[mi][ni] = (f32x4){0.f, 0.f, 0.f, 0.f};

    for (int t0 = 0; t0 < 256; t0 += 32) {
        gl_lds16(Qh + arow[0] + t0, (char*)Ah + lds0);
        gl_lds16(Qh + arow[1] + t0, (char*)Ah + lds1);
        gl_lds16(Ql + arow[0] + t0, (char*)Al + lds0);
        gl_lds16(Ql + arow[1] + t0, (char*)Al + lds1);
        gl_lds16(Kh + brow[0] + t0, (char*)Bh + lds0);
        gl_lds16(Kh + brow[1] + t0, (char*)Bh + lds1);
        gl_lds16(Kl + brow[0] + t0, (char*)Bl + lds0);
        gl_lds16(Kl + brow[1] + t0, (char*)Bl + lds1);
        __syncthreads();
        short8 ah[4], bh[4];
#pragma unroll
        for (int mi = 0; mi < 4; ++mi) ah[mi] = *(const short8*)&Ah[aoff[mi]];
#pragma unroll
        for (int ni = 0; ni < 4; ++ni) bh[ni] = *(const short8*)&Bh[boff[ni]];
#pragma unroll
        for (int mi = 0; mi < 4; ++mi)
#pragma unroll
            for (int ni = 0; ni < 4; ++ni)
                acc[mi][ni] = MFMA16(ah[mi], bh[ni], acc[mi][ni]);
        {
            short8 alv[4], blv[4];
#pragma unroll
            for (int mi = 0; mi < 4; ++mi) alv[mi] = *(const short8*)&Al[aoff[mi]];
#pragma unroll
            for (int mi = 0; mi < 4; ++mi)
#pragma unroll
                for (int ni = 0; ni < 4; ++ni)
                    acc[mi][ni] = MFMA16(alv[mi], bh[ni], acc[mi][ni]);
#pragma unroll
            for (int ni = 0; ni < 4; ++ni) blv[ni] = *(const short8*)&Bl[boff[ni]];
#pragma unroll
            for (int mi = 0; mi < 4; ++mi)
#pragma unroll
                for (int ni = 0; ni < 4; ++ni)
                    acc[mi][ni] = MFMA16(ah[mi], blv[ni], acc[mi][ni]);
        }
        __syncthreads();
    }

    float* C = Sc + nn * 262144;
#pragma unroll
    for (int mi = 0; mi < 4; ++mi) {
        int qb = q0 + (w & 1) * 64 + lq * 4 + mi * 16;
#pragma unroll
        for (int ni = 0; ni < 4; ++ni) {
            int col = k0 + (w >> 1) * 64 + ni * 16 + lm;
#pragma unroll
            for (int r = 0; r < 4; ++r)
                C[(qb + r) * 512 + col] = acc[mi][ni][r];
        }
    }
}

// ---- softmax rows of 512; fp32 in-place + bf16 copy for PV ----
__global__ __launch_bounds__(256) void k_softmax(float* __restrict__ Sc,
                                                 unsigned short* __restrict__ Ph) {
    __shared__ float red[8];
    float* p = Sc + (size_t)blockIdx.x * 512;
    unsigned short* ph = Ph + (size_t)blockIdx.x * 512;
    const int tid = threadIdx.x;
    float x0 = p[tid], x1 = p[tid + 256];
    float m = fmaxf(x0, x1);
#pragma unroll
    for (int off = 32; off; off >>= 1) m = fmaxf(m, __shfl_xor(m, off));
    if ((tid & 63) == 0) red[tid >> 6] = m;
    __syncthreads();
    m = fmaxf(fmaxf(red[0], red[1]), fmaxf(red[2], red[3]));
    float e0 = __expf(x0 - m), e1 = __expf(x1 - m);
    float s = e0 + e1;
#pragma unroll
    for (int off = 32; off; off >>= 1) s += __shfl_xor(s, off);
    if ((tid & 63) == 0) red[4 + (tid >> 6)] = s;
    __syncthreads();
    s = red[4] + red[5] + red[6] + red[7];
    float inv = 1.0f / s;
    float p0 = e0 * inv, p1 = e1 * inv;
    p[tid] = p0;
    p[tid + 256] = p1;
    ph[tid] = f2bf(p0);
    ph[tid + 256] = f2bf(p1);
}

// ---- PV: Oa[nn][q][t] = P @ V, bf16 MFMA, BM=128 BN=64 BK=32, K=512 ----
__global__ __launch_bounds__(256) void k_pv_mfma(
        const unsigned short* __restrict__ Ph, const unsigned short* __restrict__ Vt,
        float* __restrict__ Oa) {
    __shared__ __align__(16) short Ah[4096], Bh[2048];
    const int tid = threadIdx.x;
    const int w = tid >> 6, l = tid & 63;
    const int q0 = blockIdx.x * 128, t0 = blockIdx.y * 64, nn = blockIdx.z;
    const int lm = l & 15, lq = l >> 4;

    int arow[2], brow;
#pragma unroll
    for (int i = 0; i < 2; ++i) {
        int rr = w * 32 + i * 16 + (l >> 2);
        int c  = (l & 3) ^ ((rr >> 1) & 3);
        arow[i] = (nn * 512 + q0 + rr) * 512 + c * 8;
    }
    {
        int rr = w * 16 + (l >> 2);
        int c  = (l & 3) ^ ((rr >> 1) & 3);
        brow = (nn * 256 + t0 + rr) * 512 + c * 8;
    }
    const int ldsA0 = w * 2048, ldsA1 = w * 2048 + 1024, ldsB = w * 1024;

    int aoff[4], boff[2];
#pragma unroll
    for (int mi = 0; mi < 4; ++mi) {
        int row = (w & 1) * 64 + mi * 16 + lm;
        aoff[mi] = row * 32 + (lq ^ ((row >> 1) & 3)) * 8;
    }
#pragma unroll
    for (int ni = 0; ni < 2; ++ni) {
        int row = (w >> 1) * 32 + ni * 16 + lm;
        boff[ni] = row * 32 + (lq ^ ((row >> 1) & 3)) * 8;
    }

    f32x4 acc[4][2];
#pragma unroll
    for (int mi = 0; mi < 4; ++mi)
#pragma unroll
        for (int ni = 0; ni < 2; ++ni) acc[mi][ni] = (f32x4){0.f, 0.f, 0.f, 0.f};

    for (int kc = 0; kc < 512; kc += 32) {
        gl_lds16(Ph + arow[0] + kc, (char*)Ah + ldsA0);
        gl_lds16(Ph + arow[1] + kc, (char*)Ah + ldsA1);
        gl_lds16(Vt + brow + kc, (char*)Bh + ldsB);
        __syncthreads();
        short8 a[4], b[2];
#pragma unroll
        for (int mi = 0; mi < 4; ++mi) a[mi] = *(const short8*)&Ah[aoff[mi]];
#pragma unroll
        for (int ni = 0; ni < 2; ++ni) b[ni] = *(const short8*)&Bh[boff[ni]];
#pragma unroll
        for (int mi = 0; mi < 4; ++mi)
#pragma unroll
            for (int ni = 0; ni < 2; ++ni)
                acc[mi][ni] = MFMA16(a[mi], b[ni], acc[mi][ni]);
        __syncthreads();
    }

    float* C = Oa + nn * 131072;
#pragma unroll
    for (int mi = 0; mi < 4; ++mi) {
        int qb = q0 + (w & 1) * 64 + lq * 4 + mi * 16;
#pragma unroll
        for (int ni = 0; ni < 2; ++ni) {
            int tc = t0 + (w >> 1) * 32 + ni * 16 + lm;
#pragma unroll
            for (int r = 0; r < 4; ++r)
                C[(qb + r) * 256 + tc] = acc[mi][ni][r];
        }
    }
}

// ---- PV output -> padded NHWC bf16 [4][10][258][512] ----
__global__ __launch_bounds__(256) void k_prep_sp(const float* __restrict__ Oa,
                                                 unsigned short* __restrict__ Sp) {
    unsigned o = blockIdx.x * 256 + threadIdx.x;        // 4*10*258*512 exact
    unsigned ci = o & 511;
    unsigned u  = o >> 9;
    unsigned xx = u % 258u; u /= 258u;
    unsigned yy = u % 10u;
    unsigned b2 = u / 10u;
    float v = 0.f;
    if (xx >= 1 && xx <= 256 && yy >= 1 && yy <= 8) {
        unsigned ww = xx - 1, s2 = yy - 1, d2 = ci;
        unsigned nn = b2 * 8 + s2;
        unsigned qp = (ww >> 3) * 16 + (ww & 7) * 2 + (d2 >> 8);
        unsigned t  = (d2 & 7) * 32 + ((d2 >> 3) & 31);
        v = Oa[(nn * 512 + qp) * 256 + t];
    }
    Sp[o] = f2bf(v);
}

// ---- output conv, plain bf16 MFMA, BM=128 BN=64 -> Y NCHW fp32 ----
__global__ __launch_bounds__(256) void k_conv_o_mfma(
        const unsigned short* __restrict__ Sp, const unsigned short* __restrict__ Wh,
        const float* __restrict__ bias, float* __restrict__ Y) {
    __shared__ __align__(16) short Ah[4096], Bh[2048];
    const int tid = threadIdx.x;
    const int w = tid >> 6, l = tid & 63;
    const int n   = blockIdx.x >> 4;
    const int yy  = (blockIdx.x >> 1) & 7;
    const int x0  = (blockIdx.x & 1) * 128;
    const int co0 = blockIdx.y * 64;
    const int lm = l & 15, lq = l >> 4;

    int arow[2], brow;
#pragma unroll
    for (int i = 0; i < 2; ++i) {
        int rr = w * 32 + i * 16 + (l >> 2);
        int c  = (l & 3) ^ ((rr >> 1) & 3);
        arow[i] = ((n * 10 + yy + 1) * 258 + (x0 + rr + 1)) * 512 + c * 8;
    }
    {
        int rr = w * 16 + (l >> 2);
        int c  = (l & 3) ^ ((rr >> 1) & 3);
        brow = (co0 + rr) * 4608 + c * 8;
    }
    const int ldsA0 = w * 2048, ldsA1 = w * 2048 + 1024, ldsB = w * 1024;

    int aoff[4], boff[2];
#pragma unroll
    for (int mi = 0; mi < 4; ++mi) {
        int row = (w & 1) * 64 + mi * 16 + lm;
        aoff[mi] = row * 32 + (lq ^ ((row >> 1) & 3)) * 8;
    }
#pragma unroll
    for (int ni = 0; ni < 2; ++ni) {
        int row = (w >> 1) * 32 + ni * 16 + lm;
        boff[ni] = row * 32 + (lq ^ ((row >> 1) & 3)) * 8;
    }

    f32x4 acc[4][2];
#pragma unroll
    for (int ni = 0; ni < 2; ++ni) {
        float b = bias[co0 + (w >> 1) * 32 + ni * 16 + lm];
#pragma unroll
        for (int mi = 0; mi < 4; ++mi) acc[mi][ni] = (f32x4){b, b, b, b};
    }

    for (int tap = 0; tap < 9; ++tap) {
        const int tapoff = ((tap / 3 - 1) * 258 + (tap % 3 - 1)) * 512;
        const int wb = tap * 512;
        for (int ci0 = 0; ci0 < 512; ci0 += 32) {
            gl_lds16(Sp + arow[0] + tapoff + ci0, (char*)Ah + ldsA0);
            gl_lds16(Sp + arow[1] + tapoff + ci0, (char*)Ah + ldsA1);
            gl_lds16(Wh + brow + wb + ci0, (char*)Bh + ldsB);
            __syncthreads();
            short8 a[4], b[2];
#pragma unroll
            for (int mi = 0; mi < 4; ++mi) a[mi] = *(const short8*)&Ah[aoff[mi]];
#pragma unroll
            for (int ni = 0; ni < 2; ++ni) b[ni] = *(const short8*)&Bh[boff[ni]];
#pragma unroll
            for (int mi = 0; mi < 4; ++mi)
#pragma unroll
                for (int ni = 0; ni < 2; ++ni)
                    acc[mi][ni] = MFMA16(a[mi], b[ni], acc[mi][ni]);
            __syncthreads();
        }
    }

#pragma unroll
    for (int mi = 0; mi < 4; ++mi) {
        int px = x0 + (w & 1) * 64 + lq * 4 + mi * 16;
#pragma unroll
        for (int ni = 0; ni < 2; ++ni) {
            int co = co0 + (w >> 1) * 32 + ni * 16 + lm;
            *(f32x4*)&Y[n * 1048576 + co * 2048 + yy * 256 + px] = acc[mi][ni];
        }
    }
}

// ---------------------------------------------------------------------------
extern "C" void kernel_launch(void* const* d_in, const int* in_sizes, int n_in,
                              void* d_out, int out_size, void* d_ws, size_t ws_size,
                              hipStream_t stream) {
    const float* q  = (const float*)d_in[0];
    const float* k  = (const float*)d_in[1];
    const float* v  = (const float*)d_in[2];
    const float* Wq = (const float*)d_in[3];
    const float* bq = (const float*)d_in[4];
    const float* Wk = (const float*)d_in[5];
    const float* bk = (const float*)d_in[6];
    const float* Wv = (const float*)d_in[7];
    const float* bv = (const float*)d_in[8];
    const float* Wo = (const float*)d_in[9];
    const float* bo = (const float*)d_in[10];

    // ---- workspace layout (shorts); total 40,697,856 shorts = 81.4 MB ----
    unsigned short* W0  = (unsigned short*)d_ws;
    unsigned short* Wqh = W0;                   // 2359296
    unsigned short* Wql = W0 + 2359296;
    unsigned short* Wkh = W0 + 4718592;
    unsigned short* Wkl = W0 + 7077888;
    unsigned short* Wvh = W0 + 9437184;
    unsigned short* Woh = W0 + 11796480;
    unsigned short* Xvh = W0 + 14155776;        // 5570560
    unsigned short* Qh  = W0 + 19726336;        // 4194304 each
    unsigned short* Ql  = W0 + 23920640;
    unsigned short* Kh  = W0 + 28114944;
    unsigned short* Kl  = W0 + 32309248;
    unsigned short* Vt  = W0 + 36503552;
    // reuses (lifetimes verified):
    unsigned short* Ph = W0;                    // 8388608 over Wq*/Wk* (dead after conv)
    float* Oa = (float*)(W0 + 14155776);        // 4194304 f over Xvh+Qh (dead after scores)
    unsigned short* Sp = W0 + 23920640;         // 5283840 over Ql+Kh (dead after scores)

    // ---- d_out scratch: regions not yet written hold prepped inputs ----
    float* y_out = (float*)d_out;               // 4194304 floats (written last)
    float* attn  = y_out + 4194304;             // 8388608 floats (written by scores)
    unsigned short* Xqh = (unsigned short*)d_out;         // 5570560 <= 8388608 sh
    unsigned short* Xql = (unsigned short*)attn;          // 3*5570560 <= 16777216 sh
    unsigned short* Xkh = Xql + 5570560;
    unsigned short* Xkl = Xkh + 5570560;

    k_prep_w_all<<<dim3(9216, 4), 256, 0, stream>>>(Wq, Wk, Wv, Wo,
                                                    Wqh, Wql, Wkh, Wkl, Wvh, Woh);
    k_prep_x_all<<<dim3(21760, 3), 256, 0, stream>>>(q, k, v,
                                                     Xqh, Xql, Xkh, Xkl, Xvh);
    k_conv_qkv_all<<<dim3(64, 4, 3), 256, 0, stream>>>(
        Xqh, Xql, Xkh, Xkl, Xvh, Wqh, Wql, Wkh, Wkl, Wvh,
        bq, bk, bv, Qh, Ql, Kh, Kl, Vt);
    k_scores_mfma<<<dim3(4, 4, 32), 256, 0, stream>>>(Qh, Ql, Kh, Kl, attn);
    k_softmax<<<16384, 256, 0, stream>>>(attn, Ph);
    k_pv_mfma<<<dim3(4, 4, 32), 256, 0, stream>>>(Ph, Vt, Oa);
    k_prep_sp<<<20640, 256, 0, stream>>>(Oa, Sp);
    k_conv_o_mfma<<<dim3(64, 8), 256, 0, stream>>>(Sp, Woh, bo, y_out);
}